// Round 6
// baseline (160.338 us; speedup 1.0000x reference)
//
#include <hip/hip_runtime.h>
#include <stdint.h>

#define DCAP   128
#define CHUNK  256
#define LOG_TAB 19
#define TAB_SIZE (1u << LOG_TAB)
#define TAB_MASK (TAB_SIZE - 1u)
#define KEMPTY 0xFFFFFFFFu

// 0) workspace init: zeros for [degree|hist|count|neg], 0xFF for hash table.
//    Replaces two fillBuffer blits with one kernel.
__global__ __launch_bounds__(256) void k_init(uint4* __restrict__ z, int zn4,
                                              uint4* __restrict__ t, int tn4) {
    int stride = gridDim.x * 256;
    int i = blockIdx.x * 256 + threadIdx.x;
    uint4 zero = make_uint4(0u, 0u, 0u, 0u);
    uint4 ones = make_uint4(~0u, ~0u, ~0u, ~0u);
    for (int j = i; j < zn4; j += stride) z[j] = zero;
    for (int j = i; j < tn4; j += stride) t[j] = ones;
}

// 1) in-degree of each node: degree[col[e]]++
__global__ void k_degree(const int* __restrict__ col, int* __restrict__ degree, int E) {
    int e = blockIdx.x * blockDim.x + threadIdx.x;
    if (e < E) atomicAdd(&degree[col[e]], 1);
}

// 2a) per-chunk degree histogram in LDS (deg < DCAP); global atomics only for
//     the (never-occurring) deg >= DCAP tail.
__global__ void k_chunk_hist(const int* __restrict__ degree, int* __restrict__ hist,
                             int* __restrict__ chunkHist, int N) {
    __shared__ int sh[DCAP];
    int t = threadIdx.x;
    if (t < DCAP) sh[t] = 0;
    __syncthreads();
    int j = blockIdx.x * CHUNK + t;
    if (j < N) {
        int d = degree[j];
        if (d < DCAP) atomicAdd(&sh[d], 1);
        else          atomicAdd(&hist[d], 1);   // rare fallback path
    }
    __syncthreads();
    if (t < DCAP) chunkHist[blockIdx.x * DCAP + t] = sh[t];
}

// 2b) single block: totals for d<DCAP; base[d]=#{deg<d}; chunkHist -> running bases
__global__ void k_chunk_prefix(int* __restrict__ hist, int* __restrict__ chunkHist,
                               int numChunks) {
    __shared__ int stot[DCAP];
    int d = threadIdx.x;             // 0..DCAP-1
    int tot = 0;
    for (int c = 0; c < numChunks; ++c) tot += chunkHist[c * DCAP + d];
    stot[d] = tot;
    hist[d] = tot;                   // keeps k_pos_large's base sums correct
    __syncthreads();
    int run = 0;
    for (int d2 = 0; d2 < d; ++d2) run += stot[d2];
    for (int c = 0; c < numChunks; ++c) {
        int tmp = chunkHist[c * DCAP + d];
        chunkHist[c * DCAP + d] = run;   // base for chunk c, degree d
        run += tmp;
    }
}

// 2c) stable rank within chunk (deg < DCAP); CHUNK=256 keeps the O(t) scan short
__global__ void k_pos_small(const int* __restrict__ degree, const int* __restrict__ chunkBase,
                            int* __restrict__ pos, int N) {
    __shared__ int sdeg[CHUNK];
    int t = threadIdx.x;
    int j = blockIdx.x * CHUNK + t;
    int d = (j < N) ? degree[j] : -1;
    sdeg[t] = d;
    __syncthreads();
    if (j < N && d < DCAP) {
        int r = 0;
        for (int t2 = 0; t2 < t; ++t2) r += (sdeg[t2] == d);
        pos[j] = chunkBase[blockIdx.x * DCAP + d] + r;
    }
}

// 2d) fallback for deg >= DCAP (never triggered for Poisson(2) data)
__global__ void k_pos_large(const int* __restrict__ degree, const int* __restrict__ hist,
                            int* __restrict__ pos, int N, int E) {
    int d = DCAP + blockIdx.x * blockDim.x + threadIdx.x;
    if (d > E) return;
    if (hist[d] == 0) return;
    int base = 0;
    for (int d2 = 0; d2 < d; ++d2) base += hist[d2];
    int cnt = 0;
    for (int j = 0; j < N; ++j)
        if (degree[j] == d) pos[j] = base + cnt++;
}

// 3) grid-stride ballot-pack, permuted bit layout. Wave pass g covers floats
//    [g*256, g*256+256): lane l loads uint4 g*64+l (1 KB/wave/instr, coalesced).
//    Word g*8 + 2k+half, bit b  <->  float g*256 + half*128 + 4b + k.
//    4-wide unrolled body -> 4 independent dwordx4 loads in flight per wave.
__global__ __launch_bounds__(256) void k_pack_ballot(const float* __restrict__ W,
                                                     uint32_t* __restrict__ Wbits,
                                                     long long G) {
    long long wv0 = ((long long)blockIdx.x * 256 + threadIdx.x) >> 6;
    long long nwv = ((long long)gridDim.x * 256) >> 6;
    int lane = threadIdx.x & 63;
    int k = lane >> 1, half = lane & 1;          // meaningful when lane < 8
    const uint4* W4 = (const uint4*)W;
    for (long long gb = wv0 * 4; gb < G; gb += nwv * 4) {
        #pragma unroll
        for (int s = 0; s < 4; ++s) {
            long long g = gb + s;
            if (g < G) {
                uint4 u = W4[g * 64 + lane];
                unsigned long long m0 = __ballot((int)u.x < 0);
                unsigned long long m1 = __ballot((int)u.y < 0);
                unsigned long long m2 = __ballot((int)u.z < 0);
                unsigned long long m3 = __ballot((int)u.w < 0);
                if (lane < 8) {
                    unsigned long long m = (k == 0) ? m0 : (k == 1) ? m1
                                         : (k == 2) ? m2 : m3;
                    Wbits[g * 8 + lane] = half ? (uint32_t)(m >> 32) : (uint32_t)m;
                }
            }
        }
    }
}

// 3-alt) linear-layout pack fallback (only if D % 256 != 0)
__global__ __launch_bounds__(256) void k_pack_linear(const float* __restrict__ W,
                                                     uint32_t* __restrict__ Wbits, long long NW) {
    long long widx = (long long)blockIdx.x * 256 + threadIdx.x;
    if (widx >= NW) return;
    const uint4* src = (const uint4*)(W + widx * 32);
    uint32_t word = 0;
    #pragma unroll
    for (int q = 0; q < 8; ++q) {
        uint4 u = src[q];
        word |= (u.x >> 31) << (4 * q + 0);
        word |= (u.y >> 31) << (4 * q + 1);
        word |= (u.z >> 31) << (4 * q + 2);
        word |= (u.w >> 31) << (4 * q + 3);
    }
    Wbits[widx] = word;
}

// 4) dedup (min,max) edge pairs via 32-bit-key hash set; emit pos-resolved row pairs
__global__ void k_insert(const int* __restrict__ ei, const int* __restrict__ pos,
                         unsigned int* __restrict__ tab, int* __restrict__ uA,
                         int* __restrict__ uB, int* __restrict__ count, int E) {
    int e = blockIdx.x * blockDim.x + threadIdx.x;
    if (e >= E) return;
    int a = ei[e], b = ei[E + e];
    int r = min(a, b), c = max(a, b);
    unsigned int key = ((unsigned int)r << 16) | (unsigned int)c;  // N < 2^16
    unsigned int h = (key * 2654435761u) >> (32 - LOG_TAB);
    while (true) {
        unsigned int old = atomicCAS(&tab[h], KEMPTY, key);
        if (old == KEMPTY) {               // first occurrence: unique edge
            int idx = atomicAdd(count, 1);
            uA[idx] = pos[r];
            uB[idx] = pos[c];
            return;
        }
        if (old == key) return;            // duplicate
        h = (h + 1) & TAB_MASK;
    }
}

// 5) neg[w*32+d] += popcount over unique edges of xor-bit d of word w.
//    NO fences — kernel boundary provides coherence for finalize.
__global__ __launch_bounds__(256) void k_accum_bits(const uint32_t* __restrict__ Wbits,
                                                    const int* __restrict__ uA,
                                                    const int* __restrict__ uB,
                                                    const int* __restrict__ count,
                                                    int* __restrict__ neg, int D) {
    __shared__ int sneg[1024];
    int t = threadIdx.x;
    int w = t & 31;
    int slot = t >> 5;
    int wpr = D / 32;                      // words per row
    for (int i = t; i < D; i += 256) sneg[i] = 0;
    __syncthreads();
    int cnt = *count;
    int cnts[32];
    #pragma unroll
    for (int d = 0; d < 32; ++d) cnts[d] = 0;
    for (int base = blockIdx.x * 8; base < cnt; base += gridDim.x * 8) {
        int e = base + slot;
        if (e < cnt) {
            uint32_t a = Wbits[(size_t)uA[e] * wpr + w];
            uint32_t b = Wbits[(size_t)uB[e] * wpr + w];
            uint32_t x = a ^ b;
            #pragma unroll
            for (int d = 0; d < 32; ++d) cnts[d] += (x >> d) & 1u;
        }
    }
    #pragma unroll
    for (int d = 0; d < 32; ++d) atomicAdd(&sneg[w * 32 + d], cnts[d]);
    __syncthreads();
    for (int i = t; i < D; i += 256)
        if (sneg[i]) atomicAdd(&neg[i], sneg[i]);
}

// 6) out[d] = cnt - 2*neg[map(d)]  (exact integer, fits float32)
__global__ void k_finalize(const int* __restrict__ neg, const int* __restrict__ count,
                           float* __restrict__ out, int D, int permuted) {
    int d = blockIdx.x * blockDim.x + threadIdx.x;
    if (d >= D) return;
    int ni;
    if (permuted) {
        int off = d & 255, q = d >> 8;
        int k = off & 3, l = off >> 2, half = l >> 5, b = l & 31;
        ni = (q * 8 + 2 * k + half) * 32 + b;
    } else {
        ni = d;
    }
    out[d] = (float)(*count - 2 * neg[ni]);
}

static inline size_t align256(size_t x) { return (x + 255) & ~(size_t)255; }

extern "C" void kernel_launch(void* const* d_in, const int* in_sizes, int n_in,
                              void* d_out, int out_size, void* d_ws, size_t ws_size,
                              hipStream_t stream) {
    const float* W  = (const float*)d_in[0];
    const int*   ei = (const int*)d_in[1];
    const int D = out_size;               // 1024
    const int N = in_sizes[0] / D;        // 50000 (== num_nodes)
    const int E = in_sizes[1] / 2;        // 100000
    const int numChunks = (N + CHUNK - 1) / CHUNK;
    const long long ND = (long long)N * D;
    const long long NW = ND / 32;

    // zero-region: [degree | hist | count | neg], each piece 256B-aligned
    char* p = (char*)d_ws;
    char* zbase = p;
    int* degree       = (int*)p;          p += align256((size_t)N * 4);
    int* hist         = (int*)p;          p += align256((size_t)(E + 1) * 4);
    int* count        = (int*)p;          p += 256;
    int* neg          = (int*)p;          p += align256((size_t)D * 4);
    size_t zbytes = (size_t)(p - zbase);  // multiple of 256 -> /16 exact
    int* chunkHist    = (int*)p;          p += align256((size_t)numChunks * DCAP * 4);
    int* pos          = (int*)p;          p += align256((size_t)N * 4);
    unsigned int* tab = (unsigned int*)p; p += (size_t)TAB_SIZE * 4;
    int* uA           = (int*)p;          p += align256((size_t)E * 4);
    int* uB           = (int*)p;          p += align256((size_t)E * 4);
    uint32_t* Wbits   = (uint32_t*)p;     p += align256((size_t)NW * 4);

    int zn4 = (int)(zbytes / 16);
    int tn4 = (int)((size_t)TAB_SIZE * 4 / 16);
    int initGrid = (max(zn4, tn4) + 255) / 256;
    k_init<<<initGrid, 256, 0, stream>>>((uint4*)zbase, zn4, (uint4*)tab, tn4);

    k_degree<<<(E + 255) / 256, 256, 0, stream>>>(ei + E, degree, E);
    k_chunk_hist<<<numChunks, CHUNK, 0, stream>>>(degree, hist, chunkHist, N);
    k_chunk_prefix<<<1, DCAP, 0, stream>>>(hist, chunkHist, numChunks);
    k_pos_small<<<numChunks, CHUNK, 0, stream>>>(degree, chunkHist, pos, N);
    int nLarge = E + 1 - DCAP;
    k_pos_large<<<(nLarge + 255) / 256, 256, 0, stream>>>(degree, hist, pos, N, E);

    int permuted = (D % 256 == 0);
    if (permuted) {
        long long G = ND / 256;           // wave passes
        k_pack_ballot<<<2048, 256, 0, stream>>>(W, Wbits, G);
    } else {
        k_pack_linear<<<(int)((NW + 255) / 256), 256, 0, stream>>>(W, Wbits, NW);
    }

    k_insert<<<(E + 255) / 256, 256, 0, stream>>>(ei, pos, tab, uA, uB, count, E);
    k_accum_bits<<<1024, 256, 0, stream>>>(Wbits, uA, uB, count, neg, D);
    k_finalize<<<(D + 255) / 256, 256, 0, stream>>>(neg, count, (float*)d_out, D, permuted);
}

// Round 7
// 137.207 us; speedup vs baseline: 1.1686x; 1.1686x over previous
//
#include <hip/hip_runtime.h>
#include <stdint.h>

#define DCAP   128
#define CHUNK  1024
#define LOG_TAB 19
#define TAB_SIZE (1u << LOG_TAB)
#define TAB_MASK (TAB_SIZE - 1u)
#define KEMPTY 0xFFFFFFFFu

// 1) in-degree of each node: degree[col[e]]++
__global__ void k_degree(const int* __restrict__ col, int* __restrict__ degree, int E) {
    int e = blockIdx.x * blockDim.x + threadIdx.x;
    if (e < E) atomicAdd(&degree[col[e]], 1);
}

// 2a) per-chunk degree histogram in LDS (deg < DCAP); global atomics only for
//     the (never-occurring) deg >= DCAP tail.
__global__ void k_chunk_hist(const int* __restrict__ degree, int* __restrict__ hist,
                             int* __restrict__ chunkHist, int N) {
    __shared__ int sh[DCAP];
    int t = threadIdx.x;
    if (t < DCAP) sh[t] = 0;
    __syncthreads();
    int j = blockIdx.x * CHUNK + t;
    if (j < N) {
        int d = degree[j];
        if (d < DCAP) atomicAdd(&sh[d], 1);
        else          atomicAdd(&hist[d], 1);   // rare fallback path
    }
    __syncthreads();
    if (t < DCAP) chunkHist[blockIdx.x * DCAP + t] = sh[t];
}

// 2b) single block: totals for d<DCAP; base[d]=#{deg<d}; chunkHist -> running bases
__global__ void k_chunk_prefix(int* __restrict__ hist, int* __restrict__ chunkHist,
                               int numChunks) {
    __shared__ int stot[DCAP];
    int d = threadIdx.x;             // 0..DCAP-1
    int tot = 0;
    for (int c = 0; c < numChunks; ++c) tot += chunkHist[c * DCAP + d];
    stot[d] = tot;
    hist[d] = tot;                   // keeps the large-d base sums correct
    __syncthreads();
    int run = 0;
    for (int d2 = 0; d2 < d; ++d2) run += stot[d2];
    for (int c = 0; c < numChunks; ++c) {
        int tmp = chunkHist[c * DCAP + d];
        chunkHist[c * DCAP + d] = run;   // base for chunk c, degree d
        run += tmp;
    }
}

// 2c) merged: blocks [0, numChunks) -> stable intra-chunk rank (deg < DCAP);
//     blocks [numChunks, ...)      -> fallback serial rank for deg >= DCAP
//     (never triggered for Poisson(2) data; correctness net).
__global__ __launch_bounds__(CHUNK) void k_pos(const int* __restrict__ degree,
                                               const int* __restrict__ chunkBase,
                                               const int* __restrict__ hist,
                                               int* __restrict__ pos,
                                               int N, int E, int numChunks) {
    int t = threadIdx.x;
    if ((int)blockIdx.x < numChunks) {
        __shared__ int sdeg[CHUNK];
        int j = blockIdx.x * CHUNK + t;
        int d = (j < N) ? degree[j] : -1;
        sdeg[t] = d;
        __syncthreads();
        if (j < N && d < DCAP && d >= 0) {
            int r = 0;
            for (int t2 = 0; t2 < t; ++t2) r += (sdeg[t2] == d);
            pos[j] = chunkBase[blockIdx.x * DCAP + d] + r;
        }
    } else {
        int d = DCAP + (blockIdx.x - numChunks) * CHUNK + t;
        if (d > E) return;
        if (hist[d] == 0) return;
        int base = 0;
        for (int d2 = 0; d2 < d; ++d2) base += hist[d2];
        int cnt = 0;
        for (int j = 0; j < N; ++j)
            if (degree[j] == d) pos[j] = base + cnt++;
    }
}

// 3) persistent-wave ballot-pack, permuted bit layout (identical to prior rounds:
//    word g*8 + 2k+half, bit b  <->  float g*256 + 128*half + 4b + k).
//    Two-phase body: DEPTH unconditional clamp-addressed dwordx4 loads issued
//    back-to-back (8 KB in flight per wave), then ballots; only the STORE is
//    predicated (a clamped store would serialize on one address).
#define PACK_DEPTH 8
__global__ __launch_bounds__(256) void k_pack_ballot(const float* __restrict__ W,
                                                     uint32_t* __restrict__ Wbits,
                                                     long long G) {
    long long wv0 = ((long long)blockIdx.x * 256 + threadIdx.x) >> 6;
    long long nwv = ((long long)gridDim.x * 256) >> 6;
    int lane = threadIdx.x & 63;
    int k = lane >> 1, half = lane & 1;          // meaningful when lane < 8
    const uint4* W4 = (const uint4*)W;
    for (long long gb = wv0 * PACK_DEPTH; gb < G; gb += nwv * PACK_DEPTH) {
        uint4 u[PACK_DEPTH];
        #pragma unroll
        for (int s = 0; s < PACK_DEPTH; ++s) {
            long long g = gb + s;
            if (g >= G) g = G - 1;               // clamp: load stays in-bounds
            u[s] = W4[g * 64 + lane];
        }
        #pragma unroll
        for (int s = 0; s < PACK_DEPTH; ++s) {
            long long g = gb + s;
            unsigned long long m0 = __ballot((int)u[s].x < 0);
            unsigned long long m1 = __ballot((int)u[s].y < 0);
            unsigned long long m2 = __ballot((int)u[s].z < 0);
            unsigned long long m3 = __ballot((int)u[s].w < 0);
            if (g < G && lane < 8) {
                unsigned long long m = (k == 0) ? m0 : (k == 1) ? m1
                                     : (k == 2) ? m2 : m3;
                Wbits[g * 8 + lane] = half ? (uint32_t)(m >> 32) : (uint32_t)m;
            }
        }
    }
}

// 3-alt) linear-layout pack fallback (only if D % 256 != 0)
__global__ __launch_bounds__(256) void k_pack_linear(const float* __restrict__ W,
                                                     uint32_t* __restrict__ Wbits, long long NW) {
    long long widx = (long long)blockIdx.x * 256 + threadIdx.x;
    if (widx >= NW) return;
    const uint4* src = (const uint4*)(W + widx * 32);
    uint32_t word = 0;
    #pragma unroll
    for (int q = 0; q < 8; ++q) {
        uint4 u = src[q];
        word |= (u.x >> 31) << (4 * q + 0);
        word |= (u.y >> 31) << (4 * q + 1);
        word |= (u.z >> 31) << (4 * q + 2);
        word |= (u.w >> 31) << (4 * q + 3);
    }
    Wbits[widx] = word;
}

// 4) dedup (min,max) edge pairs via 32-bit-key hash set; emit pos-resolved row pairs
__global__ void k_insert(const int* __restrict__ ei, const int* __restrict__ pos,
                         unsigned int* __restrict__ tab, int* __restrict__ uA,
                         int* __restrict__ uB, int* __restrict__ count, int E) {
    int e = blockIdx.x * blockDim.x + threadIdx.x;
    if (e >= E) return;
    int a = ei[e], b = ei[E + e];
    int r = min(a, b), c = max(a, b);
    unsigned int key = ((unsigned int)r << 16) | (unsigned int)c;  // N < 2^16
    unsigned int h = (key * 2654435761u) >> (32 - LOG_TAB);
    while (true) {
        unsigned int old = atomicCAS(&tab[h], KEMPTY, key);
        if (old == KEMPTY) {               // first occurrence: unique edge
            int idx = atomicAdd(count, 1);
            uA[idx] = pos[r];
            uB[idx] = pos[c];
            return;
        }
        if (old == key) return;            // duplicate
        h = (h + 1) & TAB_MASK;
    }
}

// 5) neg[w*32+d] += popcount over unique edges of xor-bit d of word w.
//    NO fences — kernel boundary provides coherence for finalize.
__global__ __launch_bounds__(256) void k_accum_bits(const uint32_t* __restrict__ Wbits,
                                                    const int* __restrict__ uA,
                                                    const int* __restrict__ uB,
                                                    const int* __restrict__ count,
                                                    int* __restrict__ neg, int D) {
    __shared__ int sneg[1024];
    int t = threadIdx.x;
    int w = t & 31;
    int slot = t >> 5;
    int wpr = D / 32;                      // words per row
    for (int i = t; i < D; i += 256) sneg[i] = 0;
    __syncthreads();
    int cnt = *count;
    int cnts[32];
    #pragma unroll
    for (int d = 0; d < 32; ++d) cnts[d] = 0;
    for (int base = blockIdx.x * 8; base < cnt; base += gridDim.x * 8) {
        int e = base + slot;
        if (e < cnt) {
            uint32_t a = Wbits[(size_t)uA[e] * wpr + w];
            uint32_t b = Wbits[(size_t)uB[e] * wpr + w];
            uint32_t x = a ^ b;
            #pragma unroll
            for (int d = 0; d < 32; ++d) cnts[d] += (x >> d) & 1u;
        }
    }
    #pragma unroll
    for (int d = 0; d < 32; ++d) atomicAdd(&sneg[w * 32 + d], cnts[d]);
    __syncthreads();
    for (int i = t; i < D; i += 256)
        if (sneg[i]) atomicAdd(&neg[i], sneg[i]);
}

// 6) out[d] = cnt - 2*neg[map(d)]  (exact integer, fits float32)
__global__ void k_finalize(const int* __restrict__ neg, const int* __restrict__ count,
                           float* __restrict__ out, int D, int permuted) {
    int d = blockIdx.x * blockDim.x + threadIdx.x;
    if (d >= D) return;
    int ni;
    if (permuted) {
        int off = d & 255, q = d >> 8;
        int k = off & 3, l = off >> 2, half = l >> 5, b = l & 31;
        ni = (q * 8 + 2 * k + half) * 32 + b;
    } else {
        ni = d;
    }
    out[d] = (float)(*count - 2 * neg[ni]);
}

static inline size_t align256(size_t x) { return (x + 255) & ~(size_t)255; }

extern "C" void kernel_launch(void* const* d_in, const int* in_sizes, int n_in,
                              void* d_out, int out_size, void* d_ws, size_t ws_size,
                              hipStream_t stream) {
    const float* W  = (const float*)d_in[0];
    const int*   ei = (const int*)d_in[1];
    const int D = out_size;               // 1024
    const int N = in_sizes[0] / D;        // 50000 (== num_nodes)
    const int E = in_sizes[1] / 2;        // 100000
    const int numChunks = (N + CHUNK - 1) / CHUNK;
    const long long ND = (long long)N * D;
    const long long NW = ND / 32;

    // zero-region: [degree | hist | count | neg] -> ONE memset
    char* p = (char*)d_ws;
    char* zbase = p;
    int* degree       = (int*)p;          p += align256((size_t)N * 4);
    int* hist         = (int*)p;          p += align256((size_t)(E + 1) * 4);
    int* count        = (int*)p;          p += 256;
    int* neg          = (int*)p;          p += align256((size_t)D * 4);
    size_t zbytes = (size_t)(p - zbase);
    int* chunkHist    = (int*)p;          p += align256((size_t)numChunks * DCAP * 4);
    int* pos          = (int*)p;          p += align256((size_t)N * 4);
    unsigned int* tab = (unsigned int*)p; p += (size_t)TAB_SIZE * 4;
    int* uA           = (int*)p;          p += align256((size_t)E * 4);
    int* uB           = (int*)p;          p += align256((size_t)E * 4);
    uint32_t* Wbits   = (uint32_t*)p;     p += align256((size_t)NW * 4);

    hipMemsetAsync(zbase, 0, zbytes, stream);
    hipMemsetAsync(tab, 0xFF, (size_t)TAB_SIZE * 4, stream);

    k_degree<<<(E + 255) / 256, 256, 0, stream>>>(ei + E, degree, E);
    k_chunk_hist<<<numChunks, CHUNK, 0, stream>>>(degree, hist, chunkHist, N);
    k_chunk_prefix<<<1, DCAP, 0, stream>>>(hist, chunkHist, numChunks);
    int nLargeBlocks = (E + 1 - DCAP + CHUNK - 1) / CHUNK;
    k_pos<<<numChunks + nLargeBlocks, CHUNK, 0, stream>>>(degree, chunkHist, hist,
                                                          pos, N, E, numChunks);

    int permuted = (D % 256 == 0);
    if (permuted) {
        long long G = ND / 256;           // wave passes
        k_pack_ballot<<<2048, 256, 0, stream>>>(W, Wbits, G);
    } else {
        k_pack_linear<<<(int)((NW + 255) / 256), 256, 0, stream>>>(W, Wbits, NW);
    }

    k_insert<<<(E + 255) / 256, 256, 0, stream>>>(ei, pos, tab, uA, uB, count, E);
    k_accum_bits<<<1024, 256, 0, stream>>>(Wbits, uA, uB, count, neg, D);
    k_finalize<<<(D + 255) / 256, 256, 0, stream>>>(neg, count, (float*)d_out, D, permuted);
}